// Round 2
// baseline (543.639 us; speedup 1.0000x reference)
//
#include <hip/hip_runtime.h>
#include <hip/hip_bf16.h>

#define APPR_WEIGHT 0.15f
#define D_FEAT 64
#define SCAN_THREADS 1024
#define SCAN_CHUNK 128   // covers up to 131072 elements

// ---------- fallback path (round-1 atomic version) ----------
__global__ void appr_copy_kernel(const float4* __restrict__ x,
                                 float4* __restrict__ out, int n4) {
    int i = blockIdx.x * blockDim.x + threadIdx.x;
    if (i < n4) out[i] = x[i];
}

__global__ void appr_scatter_kernel(const float* __restrict__ x,
                                    const int* __restrict__ src,
                                    const int* __restrict__ dst,
                                    float* __restrict__ out,
                                    int n_edges) {
    long long idx = (long long)blockIdx.x * blockDim.x + threadIdx.x;
    long long total = (long long)n_edges * D_FEAT;
    if (idx >= total) return;
    int e = (int)(idx >> 6);
    int f = (int)(idx & 63);
    float v = APPR_WEIGHT * x[(long long)src[e] * D_FEAT + f];
    unsafeAtomicAdd(&out[(long long)dst[e] * D_FEAT + f], v);
}

// ---------- CSR path ----------

// Phase 1: histogram of dst
__global__ void hist_kernel(const int* __restrict__ dst, int* __restrict__ count,
                            int n_edges) {
    int e = blockIdx.x * blockDim.x + threadIdx.x;
    if (e < n_edges) atomicAdd(&count[dst[e]], 1);
}

// Phase 2: exclusive scan in place over n entries (single block).
// Two-level: per-thread serial chunk sums -> Hillis-Steele over thread sums ->
// per-thread serial exclusive rewrite.
__global__ void scan_kernel(int* __restrict__ data, int n) {
    __shared__ int sums[SCAN_THREADS];
    int tid = threadIdx.x;
    int base = tid * SCAN_CHUNK;

    int s = 0;
    for (int k = 0; k < SCAN_CHUNK; ++k) {
        int i = base + k;
        if (i < n) s += data[i];
    }
    sums[tid] = s;
    __syncthreads();

    // inclusive Hillis-Steele over the 1024 thread sums
    for (int off = 1; off < SCAN_THREADS; off <<= 1) {
        int t = (tid >= off) ? sums[tid - off] : 0;
        __syncthreads();
        sums[tid] += t;
        __syncthreads();
    }
    int run = sums[tid] - s;  // exclusive prefix of this thread's chunk

    for (int k = 0; k < SCAN_CHUNK; ++k) {
        int i = base + k;
        if (i < n) {
            int v = data[i];
            data[i] = run;
            run += v;
        }
    }
}

// Phase 3: scatter src ids into CSR slots
__global__ void fill_kernel(const int* __restrict__ src, const int* __restrict__ dst,
                            int* __restrict__ cursor, int* __restrict__ src_sorted,
                            int n_edges) {
    int e = blockIdx.x * blockDim.x + threadIdx.x;
    if (e < n_edges) {
        int pos = atomicAdd(&cursor[dst[e]], 1);
        src_sorted[pos] = src[e];
    }
}

// Phase 4: one wave per node, lane = feature. Gather + register accumulate,
// fused residual write: out = x + w * sum.
__global__ void aggregate_kernel(const float* __restrict__ x,
                                 const int* __restrict__ offsets,
                                 const int* __restrict__ src_sorted,
                                 float* __restrict__ out,
                                 int n_nodes) {
    int wave = (int)((blockIdx.x * (long long)blockDim.x + threadIdx.x) >> 6);
    int lane = threadIdx.x & 63;
    if (wave >= n_nodes) return;
    int beg = offsets[wave];
    int end = offsets[wave + 1];
    float sum = 0.0f;
    int j = beg;
    for (; j + 1 < end; j += 2) {
        int s0 = src_sorted[j];
        int s1 = src_sorted[j + 1];
        float v0 = x[(long long)s0 * D_FEAT + lane];
        float v1 = x[(long long)s1 * D_FEAT + lane];
        sum += v0 + v1;
    }
    if (j < end) {
        int s0 = src_sorted[j];
        sum += x[(long long)s0 * D_FEAT + lane];
    }
    long long o = (long long)wave * D_FEAT + lane;
    out[o] = x[o] + APPR_WEIGHT * sum;
}

extern "C" void kernel_launch(void* const* d_in, const int* in_sizes, int n_in,
                              void* d_out, int out_size, void* d_ws, size_t ws_size,
                              hipStream_t stream) {
    const float* x = (const float*)d_in[0];
    const int* edge_index = (const int*)d_in[1];   // [2, E] int32
    float* out = (float*)d_out;

    int n_feat_total = in_sizes[0];                // N * 64
    int n_nodes = n_feat_total / D_FEAT;
    int n_edges = in_sizes[1] / 2;

    const int* src = edge_index;                   // row 0
    const int* dst = edge_index + n_edges;         // row 1

    // ws layout: offsets[N+1] | cursor[N] | src_sorted[E]
    size_t need = (size_t)(2 * n_nodes + 1 + n_edges) * sizeof(int);
    if (ws_size < need) {
        // fallback: atomic scatter path
        int n4 = n_feat_total / 4;
        appr_copy_kernel<<<(n4 + 255) / 256, 256, 0, stream>>>(
            (const float4*)x, (float4*)out, n4);
        long long total = (long long)n_edges * D_FEAT;
        appr_scatter_kernel<<<(int)((total + 255) / 256), 256, 0, stream>>>(
            x, src, dst, out, n_edges);
        return;
    }

    int* offsets    = (int*)d_ws;                  // N+1
    int* cursor     = offsets + (n_nodes + 1);     // N
    int* src_sorted = cursor + n_nodes;            // E

    // Phase 1: zero counts + histogram
    hipMemsetAsync(offsets, 0, (size_t)(n_nodes + 1) * sizeof(int), stream);
    hist_kernel<<<(n_edges + 255) / 256, 256, 0, stream>>>(dst, offsets, n_edges);

    // Phase 2: exclusive scan -> offsets
    scan_kernel<<<1, SCAN_THREADS, 0, stream>>>(offsets, n_nodes + 1);

    // Phase 3: cursor = offsets[0..N), then fill CSR
    hipMemcpyAsync(cursor, offsets, (size_t)n_nodes * sizeof(int),
                   hipMemcpyDeviceToDevice, stream);
    fill_kernel<<<(n_edges + 255) / 256, 256, 0, stream>>>(
        src, dst, cursor, src_sorted, n_edges);

    // Phase 4: gather-aggregate, fused residual
    long long threads = (long long)n_nodes * 64;
    aggregate_kernel<<<(int)((threads + 255) / 256), 256, 0, stream>>>(
        x, offsets, src_sorted, out, n_nodes);
}

// Round 3
// 366.021 us; speedup vs baseline: 1.4853x; 1.4853x over previous
//
#include <hip/hip_runtime.h>
#include <hip/hip_bf16.h>

#define APPR_WEIGHT 0.15f
#define D_FEAT 64
#define SCAN_BLOCK 256
#define SCAN_ITEMS 4
#define SCAN_CHUNK (SCAN_BLOCK * SCAN_ITEMS)   // 1024 elems per block

// ---------- fallback path (round-1 atomic version) ----------
__global__ void appr_copy_kernel(const float4* __restrict__ x,
                                 float4* __restrict__ out, int n4) {
    int i = blockIdx.x * blockDim.x + threadIdx.x;
    if (i < n4) out[i] = x[i];
}

__global__ void appr_scatter_kernel(const float* __restrict__ x,
                                    const int* __restrict__ src,
                                    const int* __restrict__ dst,
                                    float* __restrict__ out,
                                    int n_edges) {
    long long idx = (long long)blockIdx.x * blockDim.x + threadIdx.x;
    long long total = (long long)n_edges * D_FEAT;
    if (idx >= total) return;
    int e = (int)(idx >> 6);
    int f = (int)(idx & 63);
    float v = APPR_WEIGHT * x[(long long)src[e] * D_FEAT + f];
    unsafeAtomicAdd(&out[(long long)dst[e] * D_FEAT + f], v);
}

// ---------- CSR path ----------

// Phase 1: histogram of dst
__global__ void hist_kernel(const int* __restrict__ dst, int* __restrict__ count,
                            int n_edges) {
    int e = blockIdx.x * blockDim.x + threadIdx.x;
    if (e < n_edges) atomicAdd(&count[dst[e]], 1);
}

// Phase 2a: per-block exclusive scan (in place) + block sums.
// Each thread owns SCAN_ITEMS consecutive elements -> coalesced-ish, in-block LDS scan.
__global__ void scan_partial_kernel(int* __restrict__ data,
                                    int* __restrict__ bsums, int n) {
    __shared__ int lds[SCAN_BLOCK];
    int tid = threadIdx.x;
    int base = blockIdx.x * SCAN_CHUNK + tid * SCAN_ITEMS;

    int v[SCAN_ITEMS];
    int s = 0;
#pragma unroll
    for (int k = 0; k < SCAN_ITEMS; ++k) {
        int i = base + k;
        v[k] = (i < n) ? data[i] : 0;
        s += v[k];
    }
    lds[tid] = s;
    __syncthreads();
    for (int off = 1; off < SCAN_BLOCK; off <<= 1) {
        int t = (tid >= off) ? lds[tid - off] : 0;
        __syncthreads();
        lds[tid] += t;
        __syncthreads();
    }
    int run = lds[tid] - s;                       // exclusive prefix in block
    if (tid == SCAN_BLOCK - 1) bsums[blockIdx.x] = lds[tid];  // block total
#pragma unroll
    for (int k = 0; k < SCAN_ITEMS; ++k) {
        int i = base + k;
        if (i < n) { data[i] = run; run += v[k]; }
    }
}

// Phase 2b: exclusive scan of block sums (single block, nb <= 1024)
__global__ void scan_sums_kernel(int* __restrict__ bsums, int nb) {
    __shared__ int lds[1024];
    int tid = threadIdx.x;
    int v = (tid < nb) ? bsums[tid] : 0;
    lds[tid] = v;
    __syncthreads();
    for (int off = 1; off < 1024; off <<= 1) {
        int t = (tid >= off) ? lds[tid - off] : 0;
        __syncthreads();
        lds[tid] += t;
        __syncthreads();
    }
    if (tid < nb) bsums[tid] = lds[tid] - v;      // exclusive
}

// Phase 2c: add block offsets; also write cursor copy (replaces the D2D memcpy)
__global__ void scan_finalize_kernel(int* __restrict__ data,
                                     const int* __restrict__ bsums,
                                     int* __restrict__ cursor,
                                     int n, int n_nodes) {
    int i = blockIdx.x * blockDim.x + threadIdx.x;
    if (i < n) {
        int val = data[i] + bsums[i / SCAN_CHUNK];
        data[i] = val;
        if (i < n_nodes) cursor[i] = val;
    }
}

// Phase 3: scatter src ids into CSR slots
__global__ void fill_kernel(const int* __restrict__ src, const int* __restrict__ dst,
                            int* __restrict__ cursor, int* __restrict__ src_sorted,
                            int n_edges) {
    int e = blockIdx.x * blockDim.x + threadIdx.x;
    if (e < n_edges) {
        int pos = atomicAdd(&cursor[dst[e]], 1);
        src_sorted[pos] = src[e];
    }
}

// Phase 4: one wave per node, lane = feature. Gather + register accumulate,
// fused residual write: out = x + w * sum.
__global__ void aggregate_kernel(const float* __restrict__ x,
                                 const int* __restrict__ offsets,
                                 const int* __restrict__ src_sorted,
                                 float* __restrict__ out,
                                 int n_nodes) {
    int wave = (int)((blockIdx.x * (long long)blockDim.x + threadIdx.x) >> 6);
    int lane = threadIdx.x & 63;
    if (wave >= n_nodes) return;
    int beg = offsets[wave];
    int end = offsets[wave + 1];
    float sum = 0.0f;
    int j = beg;
    for (; j + 1 < end; j += 2) {
        int s0 = src_sorted[j];
        int s1 = src_sorted[j + 1];
        float v0 = x[(long long)s0 * D_FEAT + lane];
        float v1 = x[(long long)s1 * D_FEAT + lane];
        sum += v0 + v1;
    }
    if (j < end) {
        sum += x[(long long)src_sorted[j] * D_FEAT + lane];
    }
    long long o = (long long)wave * D_FEAT + lane;
    out[o] = x[o] + APPR_WEIGHT * sum;
}

extern "C" void kernel_launch(void* const* d_in, const int* in_sizes, int n_in,
                              void* d_out, int out_size, void* d_ws, size_t ws_size,
                              hipStream_t stream) {
    const float* x = (const float*)d_in[0];
    const int* edge_index = (const int*)d_in[1];   // [2, E] int32
    float* out = (float*)d_out;

    int n_feat_total = in_sizes[0];                // N * 64
    int n_nodes = n_feat_total / D_FEAT;
    int n_edges = in_sizes[1] / 2;

    const int* src = edge_index;                   // row 0
    const int* dst = edge_index + n_edges;         // row 1

    int n_off = n_nodes + 1;
    int nb = (n_off + SCAN_CHUNK - 1) / SCAN_CHUNK;

    // ws layout: offsets[N+1] | cursor[N] | src_sorted[E] | bsums[nb]
    size_t need = (size_t)(2 * n_nodes + 1 + n_edges + nb) * sizeof(int);
    if (ws_size < need) {
        int n4 = n_feat_total / 4;
        appr_copy_kernel<<<(n4 + 255) / 256, 256, 0, stream>>>(
            (const float4*)x, (float4*)out, n4);
        long long total = (long long)n_edges * D_FEAT;
        appr_scatter_kernel<<<(int)((total + 255) / 256), 256, 0, stream>>>(
            x, src, dst, out, n_edges);
        return;
    }

    int* offsets    = (int*)d_ws;                  // N+1
    int* cursor     = offsets + n_off;             // N
    int* src_sorted = cursor + n_nodes;            // E
    int* bsums      = src_sorted + n_edges;        // nb

    // Phase 1: zero counts + histogram
    hipMemsetAsync(offsets, 0, (size_t)n_off * sizeof(int), stream);
    hist_kernel<<<(n_edges + 255) / 256, 256, 0, stream>>>(dst, offsets, n_edges);

    // Phase 2: multi-block exclusive scan -> offsets (+ cursor copy)
    scan_partial_kernel<<<nb, SCAN_BLOCK, 0, stream>>>(offsets, bsums, n_off);
    scan_sums_kernel<<<1, 1024, 0, stream>>>(bsums, nb);
    scan_finalize_kernel<<<(n_off + 255) / 256, 256, 0, stream>>>(
        offsets, bsums, cursor, n_off, n_nodes);

    // Phase 3: fill CSR
    fill_kernel<<<(n_edges + 255) / 256, 256, 0, stream>>>(
        src, dst, cursor, src_sorted, n_edges);

    // Phase 4: gather-aggregate, fused residual
    long long threads = (long long)n_nodes * 64;
    aggregate_kernel<<<(int)((threads + 255) / 256), 256, 0, stream>>>(
        x, offsets, src_sorted, out, n_nodes);
}